// Round 4
// baseline (78.109 us; speedup 1.0000x reference)
//
#include <hip/hip_runtime.h>

#define SEQ_L 4096
#define BATCH 4
#define DMODEL 512
#define CUT 0.055f            // normalized gap beyond which exp(s-100) < 5e-14
#define RPW 8                 // score rows per wave
#define RPB 32                // score rows per block (4 waves)
#define SCORE_BLOCKS (BATCH * SEQ_L / RPB)     // 512
#define EMB_BLOCKS 512
#define EMB_RPB (BATCH * SEQ_L / EMB_BLOCKS)   // 32

typedef float f4 __attribute__((ext_vector_type(4)));

__device__ __forceinline__ void nt_store4(f4* p, f4 v) {
    __builtin_nontemporal_store(v, p);
}

// Fused kernel. Blocks [0, SCORE_BLOCKS): softmax score rows; blocks
// [SCORE_BLOCKS, +EMB_BLOCKS): embedding.
// Scores math: t = time/200; s = 100*exp(-((ti-tj)^2)^2*40000); causal
// softmax. Row max is exactly 100 (diagonal), masked/far terms are exact
// fp32 zeros; sorted times => non-negligible columns = contiguous [jlo, i].
__global__ __launch_bounds__(256) void fused_kernel(const int* __restrict__ et,
                                                    const float* __restrict__ tm,
                                                    const float* __restrict__ tab,
                                                    float* __restrict__ scores,
                                                    float* __restrict__ emb) {
    if (blockIdx.x < SCORE_BLOCKS) {
        // ---------------- scores path ----------------
        __shared__ float ts[SEQ_L];
        const int b  = blockIdx.x / (SEQ_L / RPB);
        const int i0 = (blockIdx.x % (SEQ_L / RPB)) * RPB;

        const f4* tb4 = (const f4*)(tm + b * SEQ_L);
        f4* ts4 = (f4*)ts;
        #pragma unroll
        for (int q = 0; q < 4; ++q) {
            int j = threadIdx.x + q * 256;
            ts4[j] = tb4[j] * (1.0f / 200.0f);
        }
        __syncthreads();

        const int wave = threadIdx.x >> 6;
        const int lane = threadIdx.x & 63;
        const int ibase = i0 + wave * RPW;

        // ---- phase 1: per-row params (jlo, inv_denom, ti) into registers ----
        float tiR[RPW], invR[RPW];
        int   jloR[RPW];

        int jlo;
        {   // binary search once per wave for the first row
            const float tc = ts[ibase] - CUT;
            int lo = 0, hi = ibase;
            while (lo < hi) {
                int mid = (lo + hi) >> 1;
                if (ts[mid] < tc) lo = mid + 1; else hi = mid;
            }
            jlo = lo;
        }

        #pragma unroll
        for (int r = 0; r < RPW; ++r) {
            const int i = ibase + r;
            const float ti = ts[i];
            const float tc = ti - CUT;
            // ballot-based monotone advance (prefix-true predicate)
            for (;;) {
                int idx = jlo + lane; if (idx > SEQ_L - 1) idx = SEQ_L - 1;
                int cnt = __popcll(__ballot(ts[idx] < tc));
                jlo += cnt;
                if (cnt < 64) break;
            }
            float sum = 0.0f;
            for (int j = jlo + lane; j <= i; j += 64) {
                float d = ti - ts[j];
                float d2 = d * d;
                float s = 100.0f * __expf(-(d2 * d2) * 40000.0f);
                sum += __expf(s - 100.0f);
            }
            #pragma unroll
            for (int off = 1; off < 64; off <<= 1) sum += __shfl_xor(sum, off, 64);
            tiR[r] = ti; invR[r] = 1.0f / sum; jloR[r] = jlo;
        }

        // ---- phase 2: pure streaming stores (branch-free segments) ----
        #pragma unroll
        for (int r = 0; r < RPW; ++r) {
            const int i = ibase + r;
            const float ti = tiR[r], inv = invR[r];
            const int jl = jloR[r];
            const int c_lo = jl >> 2, c_hi = i >> 2;
            f4* out4 = (f4*)(scores + ((size_t)(b * SEQ_L + i)) * SEQ_L);
            const f4 z = {0.0f, 0.0f, 0.0f, 0.0f};

            for (int c = lane; c < c_lo; c += 64)            // left zeros
                nt_store4(out4 + c, z);
            for (int c = c_lo + lane; c <= c_hi; c += 64) {  // band
                f4 tv = ts4[c];
                f4 v;
                #pragma unroll
                for (int q = 0; q < 4; ++q) {
                    const int jj = 4 * c + q;
                    float d = ti - tv[q];
                    float d2 = d * d;
                    float s = 100.0f * __expf(-(d2 * d2) * 40000.0f);
                    float p = __expf(s - 100.0f) * inv;
                    v[q] = (jj >= jl && jj <= i) ? p : 0.0f;
                }
                nt_store4(out4 + c, v);
            }
            for (int c = c_hi + 1 + lane; c < SEQ_L / 4; c += 64)  // right zeros
                nt_store4(out4 + c, z);
        }
    } else {
        // ---------------- embedding path ----------------
        const int t = threadIdx.x;
        const bool temporal = t < 128;

        float ipA = 0.0f, ipB = 0.0f;
        if (temporal) {
            const float c = -13.287712379549449f / 256.0f;   // -log2(10000)/256
            ipA = exp2f(c * (float)(2 * t));
            ipB = exp2f(c * (float)(2 * t + 1));
        }
        const int ecol = (t - 128) * 4;

        const int bl0 = ((int)blockIdx.x - SCORE_BLOCKS) * EMB_RPB;
        for (int r = 0; r < EMB_RPB; ++r) {
            const int bl = bl0 + r;
            f4 v;
            if (temporal) {
                const float time = tm[bl];
                const float a = time * ipA;
                const float bp = time * ipB;
                v[0] = __sinf(a);  v[1] = __cosf(a);
                v[2] = __sinf(bp); v[3] = __cosf(bp);
            } else {
                f4 e = *(const f4*)(tab + et[bl] * DMODEL + ecol);
                v = e * 22.627416997969522f;                 // sqrt(512)
            }
            nt_store4((f4*)(emb + (size_t)bl * 2 * DMODEL) + t, v);
        }
    }
}

extern "C" void kernel_launch(void* const* d_in, const int* in_sizes, int n_in,
                              void* d_out, int out_size, void* d_ws, size_t ws_size,
                              hipStream_t stream) {
    const int*   event_type = (const int*)d_in[0];
    const float* event_time = (const float*)d_in[1];
    const float* emb_table  = (const float*)d_in[2];

    float* scores = (float*)d_out;
    float* emb    = scores + (size_t)BATCH * SEQ_L * SEQ_L;

    fused_kernel<<<SCORE_BLOCKS + EMB_BLOCKS, 256, 0, stream>>>(
        event_type, event_time, emb_table, scores, emb);
}

// Round 5
// 67.302 us; speedup vs baseline: 1.1606x; 1.1606x over previous
//
#include <hip/hip_runtime.h>

#define SEQ_L 4096
#define BATCH 4
#define DMODEL 512
#define CUT 0.055f            // normalized gap beyond which exp(s-100) < 5e-14
#define RPW 4                 // score rows per wave
#define RPB 16                // score rows per block (4 waves)
#define SCORE_BLOCKS (BATCH * SEQ_L / RPB)     // 1024
#define EMB_BLOCKS 512
#define EMB_RPB (BATCH * SEQ_L / EMB_BLOCKS)   // 32

typedef float f4 __attribute__((ext_vector_type(4)));

// Fused kernel. Blocks [0, SCORE_BLOCKS): softmax score rows; blocks
// [SCORE_BLOCKS, +EMB_BLOCKS): embedding.
// Scores math: t = time/200; s = 100*exp(-((ti-tj)^2)^2*40000); causal
// softmax. Row max is exactly 100 (diagonal), masked/far terms are exact
// fp32 zeros; sorted times => non-negligible columns = contiguous [jlo, i].
//
// Per-wave schedule (stores are fire-and-forget; no waitcnt until kernel
// end since zero-segments and band segments are address-disjoint):
//   P0: stage ts, per-row jlo (one binary search + ballot advances)
//   P1: issue ALL zero-segment stores for the wave's 4 rows (~56 KB)
//   P2: denominators for the 4 rows  <- overlaps P1's store drain
//   P3: band stores (~230 cols/row)
__global__ __launch_bounds__(256) void fused_kernel(const int* __restrict__ et,
                                                    const float* __restrict__ tm,
                                                    const float* __restrict__ tab,
                                                    float* __restrict__ scores,
                                                    float* __restrict__ emb) {
    if (blockIdx.x < SCORE_BLOCKS) {
        // ---------------- scores path ----------------
        __shared__ float ts[SEQ_L];
        const int b  = blockIdx.x / (SEQ_L / RPB);
        const int i0 = (blockIdx.x % (SEQ_L / RPB)) * RPB;

        const f4* tb4 = (const f4*)(tm + b * SEQ_L);
        f4* ts4 = (f4*)ts;
        #pragma unroll
        for (int q = 0; q < 4; ++q) {
            int j = threadIdx.x + q * 256;
            ts4[j] = tb4[j] * (1.0f / 200.0f);
        }
        __syncthreads();

        const int wave = threadIdx.x >> 6;
        const int lane = threadIdx.x & 63;
        const int ibase = i0 + wave * RPW;

        // ---- P0: per-row jlo ----
        int   jloR[RPW];
        float tiR[RPW];
        int jlo;
        {
            const float tc = ts[ibase] - CUT;
            int lo = 0, hi = ibase;
            while (lo < hi) {
                int mid = (lo + hi) >> 1;
                if (ts[mid] < tc) lo = mid + 1; else hi = mid;
            }
            jlo = lo;
        }
        #pragma unroll
        for (int r = 0; r < RPW; ++r) {
            const float ti = ts[ibase + r];
            const float tc = ti - CUT;
            for (;;) {  // ballot-based monotone advance (prefix-true predicate)
                int idx = jlo + lane; if (idx > SEQ_L - 1) idx = SEQ_L - 1;
                int cnt = __popcll(__ballot(ts[idx] < tc));
                jlo += cnt;
                if (cnt < 64) break;
            }
            jloR[r] = jlo; tiR[r] = ti;
        }

        // ---- P1: zero-segment stores for all rows (bulk of the bytes) ----
        const f4 z = {0.0f, 0.0f, 0.0f, 0.0f};
        #pragma unroll
        for (int r = 0; r < RPW; ++r) {
            const int i = ibase + r;
            const int c_lo = jloR[r] >> 2, c_hi = i >> 2;
            f4* out4 = (f4*)(scores + ((size_t)(b * SEQ_L + i)) * SEQ_L);
            for (int c = lane; c < c_lo; c += 64)                  out4[c] = z;
            for (int c = c_hi + 1 + lane; c < SEQ_L / 4; c += 64)  out4[c] = z;
        }

        // ---- P2: denominators (overlaps P1 store drain) ----
        float invR[RPW];
        #pragma unroll
        for (int r = 0; r < RPW; ++r) {
            const int i = ibase + r;
            const float ti = tiR[r];
            float sum = 0.0f;
            for (int j = jloR[r] + lane; j <= i; j += 64) {
                float d = ti - ts[j];
                float d2 = d * d;
                float s = 100.0f * __expf(-(d2 * d2) * 40000.0f);
                sum += __expf(s - 100.0f);
            }
            #pragma unroll
            for (int off = 1; off < 64; off <<= 1) sum += __shfl_xor(sum, off, 64);
            invR[r] = 1.0f / sum;
        }

        // ---- P3: band stores ----
        #pragma unroll
        for (int r = 0; r < RPW; ++r) {
            const int i = ibase + r;
            const float ti = tiR[r], inv = invR[r];
            const int jl = jloR[r];
            const int c_lo = jl >> 2, c_hi = i >> 2;
            f4* out4 = (f4*)(scores + ((size_t)(b * SEQ_L + i)) * SEQ_L);
            for (int c = c_lo + lane; c <= c_hi; c += 64) {
                f4 tv = ts4[c];
                f4 v;
                #pragma unroll
                for (int q = 0; q < 4; ++q) {
                    const int jj = 4 * c + q;
                    float d = ti - tv[q];
                    float d2 = d * d;
                    float s = 100.0f * __expf(-(d2 * d2) * 40000.0f);
                    float p = __expf(s - 100.0f) * inv;
                    v[q] = (jj >= jl && jj <= i) ? p : 0.0f;
                }
                out4[c] = v;
            }
        }
    } else {
        // ---------------- embedding path ----------------
        const int t = threadIdx.x;
        const bool temporal = t < 128;

        float ipA = 0.0f, ipB = 0.0f;
        if (temporal) {
            const float c = -13.287712379549449f / 256.0f;   // -log2(10000)/256
            ipA = exp2f(c * (float)(2 * t));
            ipB = exp2f(c * (float)(2 * t + 1));
        }
        const int ecol = (t - 128) * 4;

        const int bl0 = ((int)blockIdx.x - SCORE_BLOCKS) * EMB_RPB;
        for (int r = 0; r < EMB_RPB; ++r) {
            const int bl = bl0 + r;
            f4 v;
            if (temporal) {
                const float time = tm[bl];
                const float a = time * ipA;
                const float bp = time * ipB;
                v[0] = __sinf(a);  v[1] = __cosf(a);
                v[2] = __sinf(bp); v[3] = __cosf(bp);
            } else {
                f4 e = *(const f4*)(tab + et[bl] * DMODEL + ecol);
                v = e * 22.627416997969522f;                 // sqrt(512)
            }
            ((f4*)(emb + (size_t)bl * 2 * DMODEL))[t] = v;
        }
    }
}

extern "C" void kernel_launch(void* const* d_in, const int* in_sizes, int n_in,
                              void* d_out, int out_size, void* d_ws, size_t ws_size,
                              hipStream_t stream) {
    const int*   event_type = (const int*)d_in[0];
    const float* event_time = (const float*)d_in[1];
    const float* emb_table  = (const float*)d_in[2];

    float* scores = (float*)d_out;
    float* emb    = scores + (size_t)BATCH * SEQ_L * SEQ_L;

    fused_kernel<<<SCORE_BLOCKS + EMB_BLOCKS, 256, 0, stream>>>(
        event_type, event_time, emb_table, scores, emb);
}